// Round 8
// baseline (144.074 us; speedup 1.0000x reference)
//
#include <hip/hip_runtime.h>

// out[N,32] = scatter_add over edges e: values[e] * x[cols[e], :] into row rows[e]
//
// Pipeline (superbucket = row >> 7, 128 rows, nb128 = ceil(N/128) = 782):
//   k1 hist128 : per-WG LDS histogram of superbuckets -> global counts
//   k2 scan128 : single-WG exclusive scan (782 <= 1024) -> sstart, cursor
//   k3 bin8    : CHUNK=16384 edges; 8 WGs per chunk, each owning buckets with
//                b%8==sub. Long runs (~21 edges = ~168B) -> mostly full-line
//                writes -> low write-amp; split restores WG-level parallelism.
//   k4 spmm4   : FOUR WGs per superbucket (grid = nb32 = 3125). Each WG streams
//                the full run, keeps entries with rloc7>>5 == its sub-slot,
//                LDS counting-sorts by low 5 row bits, then each 8-lane group
//                owns ONE row and accumulates in registers. No float atomics.
//
// indices: d_in[0] = int[2*NNZ], values: d_in[1] = float[NNZ], x: d_in[2] = float[N*32]

#define D 32
#define SBSHIFT 7
#define BSHIFT 5
#define RPB 32                  // rows per spmm bucket
#define NB128_MAX 1024
#define CHUNK_H 4096            // edges per workgroup in hist
#define CHUNK_B 16384           // edges per chunk in bin
#define NSPLIT 8                // WGs per bin chunk (bucket-mod split)
#define MAXE 1024               // sort-chunk size in spmm

typedef unsigned long long ull;

// ---------- k1: superbucket histogram with LDS pre-aggregation ----------
__global__ __launch_bounds__(256) void hist128_kernel(
    const int* __restrict__ idx, int* __restrict__ gcnt, int nnz, int nb)
{
    __shared__ int lcnt[NB128_MAX];
    for (int i = threadIdx.x; i < nb; i += 256) lcnt[i] = 0;
    __syncthreads();
    int base = blockIdx.x * CHUNK_H;
    int end = min(base + CHUNK_H, nnz);
    for (int e = base + threadIdx.x; e < end; e += 256)
        atomicAdd(&lcnt[idx[e] >> SBSHIFT], 1);
    __syncthreads();
    for (int i = threadIdx.x; i < nb; i += 256) {
        int c = lcnt[i];
        if (c) atomicAdd(&gcnt[i], c);
    }
}

// ---------- k2: exclusive scan of superbucket counts (nb <= 1024) ----------
__global__ __launch_bounds__(1024) void scan128_kernel(
    const int* __restrict__ gcnt, int* __restrict__ sstart,
    int* __restrict__ cursor, int nb)
{
    __shared__ int sm[1024];
    int v = ((int)threadIdx.x < nb) ? gcnt[threadIdx.x] : 0;
    sm[threadIdx.x] = v;
    __syncthreads();
    for (int off = 1; off < 1024; off <<= 1) {
        int t = sm[threadIdx.x];
        int u = ((int)threadIdx.x >= off) ? sm[threadIdx.x - off] : 0;
        __syncthreads();
        sm[threadIdx.x] = t + u;
        __syncthreads();
    }
    if ((int)threadIdx.x < nb) {
        int ex = sm[threadIdx.x] - v;
        sstart[threadIdx.x] = ex;
        cursor[threadIdx.x] = ex;
    }
    if (threadIdx.x == 1023) sstart[nb] = sm[1023];
}

// ---------- k3: bucket-mod-split bin scatter, long runs ----------
__global__ __launch_bounds__(256) void bin8_kernel(
    const int* __restrict__ idx, const float* __restrict__ vals,
    int* __restrict__ gcursor, ull* __restrict__ packed,
    int nnz, int nb)
{
    __shared__ int lcnt[NB128_MAX / NSPLIT];
    __shared__ int lbase[NB128_MAX / NSPLIT];
    int chunk = blockIdx.x >> 3;
    int sub   = blockIdx.x & (NSPLIT - 1);
    int base = chunk * CHUNK_B;
    int end = min(base + CHUNK_B, nnz);
    int nloc = (nb - sub + NSPLIT - 1) / NSPLIT;   // buckets with b%8==sub

    for (int i = threadIdx.x; i < nloc; i += 256) lcnt[i] = 0;
    __syncthreads();

    // pass 1: count my buckets' edges in this chunk
    for (int e = base + threadIdx.x; e < end; e += 256) {
        int b = idx[e] >> SBSHIFT;
        if ((b & (NSPLIT - 1)) == sub) atomicAdd(&lcnt[b >> 3], 1);
    }
    __syncthreads();

    // reserve contiguous runs
    for (int i = threadIdx.x; i < nloc; i += 256) {
        int c = lcnt[i];
        lbase[i] = c ? atomicAdd(&gcursor[(i << 3) | sub], c) : 0;
        lcnt[i] = 0;                       // reuse as intra-WG cursor
    }
    __syncthreads();

    // pass 2: scatter my buckets' edges into their runs
    for (int e = base + threadIdx.x; e < end; e += 256) {
        int r = idx[e];
        int b = r >> SBSHIFT;
        if ((b & (NSPLIT - 1)) != sub) continue;
        int li = b >> 3;
        int pos = lbase[li] + atomicAdd(&lcnt[li], 1);
        unsigned c = (unsigned)idx[nnz + e];
        unsigned vb = __float_as_uint(vals[e]);
        packed[pos] = ((ull)vb << 32) | ((ull)c << SBSHIFT) | (unsigned)(r & 127);
    }
}

// ---------- k4: filtered counting-sort + register-accumulate SpMM ----------
__global__ __launch_bounds__(256) void spmm4_kernel(
    const int* __restrict__ sstart,
    const ull* __restrict__ packed,
    const float* __restrict__ x, float* __restrict__ out, int N)
{
    __shared__ ull sp[MAXE];       // row-sorted slice of this chunk
    __shared__ int cnt[RPB];
    __shared__ int off[RPB];
    __shared__ int cur[RPB];

    int b = blockIdx.x;            // 32-row bucket id
    int j = b >> 2;                // superbucket
    int mysub = b & 3;             // which 32-row slice of the 128
    int s = sstart[j];
    int e = sstart[j + 1];
    int g = threadIdx.x >> 3;      // group = owned row-local index (32 groups)
    int q = threadIdx.x & 7;       // 4 columns each
    const float4* __restrict__ x4 = reinterpret_cast<const float4*>(x);

    float4 acc = make_float4(0.f, 0.f, 0.f, 0.f);

    for (int base = s; base < e; base += MAXE) {
        int m = min(MAXE, e - base);

        if (threadIdx.x < RPB) cnt[threadIdx.x] = 0;
        __syncthreads();

        // filtered hist (keep matching entries in registers for the scatter pass)
        ull pv[MAXE / 256];
        bool have[MAXE / 256];
        #pragma unroll
        for (int jj = 0; jj < MAXE / 256; ++jj) {
            int i = threadIdx.x + jj * 256;
            have[jj] = false;
            if (i < m) {
                ull p = packed[base + i];
                if ((int)((p >> BSHIFT) & 3) == mysub) {   // bits 5..6 of rloc7
                    pv[jj] = p;
                    have[jj] = true;
                    atomicAdd(&cnt[(int)(p & (RPB - 1))], 1);
                }
            }
        }
        __syncthreads();

        // exclusive scan of 32 counters (lanes 0..31 of wave 0)
        if (threadIdx.x < RPB) {
            int v = cnt[threadIdx.x];
            int sum = v;
            #pragma unroll
            for (int d = 1; d < RPB; d <<= 1) {
                int u = __shfl_up(sum, d, 64);
                if ((int)threadIdx.x >= d) sum += u;
            }
            off[threadIdx.x] = sum - v;
            cur[threadIdx.x] = sum - v;
        }
        __syncthreads();

        // scatter my slice into row-sorted order
        #pragma unroll
        for (int jj = 0; jj < MAXE / 256; ++jj) {
            if (have[jj]) {
                int rl = (int)(pv[jj] & (RPB - 1));
                int pos = atomicAdd(&cur[rl], 1);
                sp[pos] = pv[jj];
            }
        }
        __syncthreads();

        // group g accumulates its own row's segment — registers, no atomics
        int rs = off[g];
        int re = rs + cnt[g];
        int k = rs;
        for (; k + 3 < re; k += 4) {       // 4 gathers in flight
            ull p0 = sp[k], p1 = sp[k + 1], p2 = sp[k + 2], p3 = sp[k + 3];
            int c0 = (int)((p0 >> SBSHIFT) & 0x1ffff);
            int c1 = (int)((p1 >> SBSHIFT) & 0x1ffff);
            int c2 = (int)((p2 >> SBSHIFT) & 0x1ffff);
            int c3 = (int)((p3 >> SBSHIFT) & 0x1ffff);
            float v0 = __uint_as_float((unsigned)(p0 >> 32));
            float v1 = __uint_as_float((unsigned)(p1 >> 32));
            float v2 = __uint_as_float((unsigned)(p2 >> 32));
            float v3 = __uint_as_float((unsigned)(p3 >> 32));
            float4 a0 = x4[(size_t)c0 * (D / 4) + q];
            float4 a1 = x4[(size_t)c1 * (D / 4) + q];
            float4 a2 = x4[(size_t)c2 * (D / 4) + q];
            float4 a3 = x4[(size_t)c3 * (D / 4) + q];
            acc.x += v0 * a0.x; acc.y += v0 * a0.y; acc.z += v0 * a0.z; acc.w += v0 * a0.w;
            acc.x += v1 * a1.x; acc.y += v1 * a1.y; acc.z += v1 * a1.z; acc.w += v1 * a1.w;
            acc.x += v2 * a2.x; acc.y += v2 * a2.y; acc.z += v2 * a2.z; acc.w += v2 * a2.w;
            acc.x += v3 * a3.x; acc.y += v3 * a3.y; acc.z += v3 * a3.z; acc.w += v3 * a3.w;
        }
        for (; k < re; ++k) {
            ull p = sp[k];
            int c = (int)((p >> SBSHIFT) & 0x1ffff);
            float v = __uint_as_float((unsigned)(p >> 32));
            float4 a = x4[(size_t)c * (D / 4) + q];
            acc.x += v * a.x; acc.y += v * a.y; acc.z += v * a.z; acc.w += v * a.w;
        }
        __syncthreads();   // protect sp/cnt before next chunk
    }

    int row = (j << SBSHIFT) + (mysub << BSHIFT) + g;
    if (row < N)
        reinterpret_cast<float4*>(out)[(size_t)row * (D / 4) + q] = acc;
}

// ---------- fallback: direct atomic scatter (round-1) ----------
__global__ __launch_bounds__(256) void spmm_scatter_kernel(
    const int* __restrict__ idx, const float* __restrict__ vals,
    const float* __restrict__ x, float* __restrict__ out, int nnz)
{
    int t = blockIdx.x * blockDim.x + threadIdx.x;
    int e = t >> 3;
    int q = t & 7;
    if (e >= nnz) return;
    int r = idx[e];
    int c = idx[nnz + e];
    float v = vals[e];
    const float4 xv = reinterpret_cast<const float4*>(x)[(size_t)c * (D / 4) + q];
    float* o = out + (size_t)r * D + q * 4;
    atomicAdd(o + 0, v * xv.x);
    atomicAdd(o + 1, v * xv.y);
    atomicAdd(o + 2, v * xv.z);
    atomicAdd(o + 3, v * xv.w);
}

static inline size_t align256(size_t v) { return (v + 255) & ~(size_t)255; }

extern "C" void kernel_launch(void* const* d_in, const int* in_sizes, int n_in,
                              void* d_out, int out_size, void* d_ws, size_t ws_size,
                              hipStream_t stream)
{
    const int* idx   = (const int*)d_in[0];
    const float* val = (const float*)d_in[1];
    const float* x   = (const float*)d_in[2];
    float* out       = (float*)d_out;

    const int nnz  = in_sizes[1];
    const int N    = out_size / D;
    const int nb128 = (N + 127) >> SBSHIFT;   // superbuckets
    const int nb32  = (N + 31) >> BSHIFT;     // spmm buckets (grid)

    size_t off_cnt    = 0;
    size_t off_sstart = align256(off_cnt    + (size_t)nb128 * 4);
    size_t off_cursor = align256(off_sstart + (size_t)(nb128 + 1) * 4);
    size_t off_packed = align256(off_cursor + (size_t)nb128 * 4);
    size_t ws_needed  = off_packed + (size_t)nnz * 8;

    // col must fit 17 bits, nb128 must fit scan width
    if (ws_size < ws_needed || nb128 > NB128_MAX || N > 131072) {
        hipMemsetAsync(d_out, 0, (size_t)out_size * sizeof(float), stream);
        const long long total = (long long)nnz * 8;
        spmm_scatter_kernel<<<(int)((total + 255) / 256), 256, 0, stream>>>(
            idx, val, x, out, nnz);
        return;
    }

    char* ws = (char*)d_ws;
    int* gcnt   = (int*)(ws + off_cnt);
    int* sstart = (int*)(ws + off_sstart);
    int* cursor = (int*)(ws + off_cursor);
    ull* packed = (ull*)(ws + off_packed);

    hipMemsetAsync(gcnt, 0, (size_t)nb128 * 4, stream);

    const int nchunk_h = (nnz + CHUNK_H - 1) / CHUNK_H;
    const int nchunk_b = (nnz + CHUNK_B - 1) / CHUNK_B;
    hist128_kernel<<<nchunk_h, 256, 0, stream>>>(idx, gcnt, nnz, nb128);
    scan128_kernel<<<1, 1024, 0, stream>>>(gcnt, sstart, cursor, nb128);
    bin8_kernel<<<nchunk_b * NSPLIT, 256, 0, stream>>>(idx, val, cursor, packed, nnz, nb128);
    spmm4_kernel<<<nb32, 256, 0, stream>>>(sstart, packed, x, out, N);
}

// Round 9
// 73.774 us; speedup vs baseline: 1.9529x; 1.9529x over previous
//
#include <hip/hip_runtime.h>

// out[N,32] = scatter_add over edges e: values[e] * x[cols[e], :] into row rows[e]
//
// Pipeline (superbucket = row >> 7, 128 rows, nb128 = ceil(N/128) = 782):
//   k1 bin_sorted : one WG per 4096-edge chunk. LDS counting sort by superbucket
//                   (counters+scan in LDS, edges in registers), then CONTIGUOUS
//                   write of the sorted chunk into packed[chunk*4096..] (write-amp
//                   1.0) + per-(chunk,bucket) ushort segment starts into desc.
//                   No global histogram / scan / cursors / memset at all.
//   k2 spmm_seg   : FOUR WGs per superbucket (grid = nb32 = 3125). Each WG builds
//                   its superbucket's segment table (scan of 391 segment lengths),
//                   streams edges via binary-search segment walk, keeps entries
//                   with rloc bits5..6 == sub-slot, LDS counting-sorts by low 5
//                   row bits, then each 8-lane group owns ONE row and accumulates
//                   in registers. No float atomics anywhere.
//
// indices: d_in[0] = int[2*NNZ], values: d_in[1] = float[NNZ], x: d_in[2] = float[N*32]

#define D 32
#define SBSHIFT 7
#define BSHIFT 5
#define RPB 32                  // rows per spmm bucket
#define NB128_MAX 1024
#define CHUNK 4096              // edges per bin chunk (sorted unit)
#define EPT (CHUNK / 256)       // 16 edges per thread in bin
#define NCH_MAX 512             // max chunks (nnz <= 2.1M)
#define MAXE 1024               // sort-batch size in spmm

typedef unsigned long long ull;

// ---------- k1: per-chunk counting sort by superbucket ----------
__global__ __launch_bounds__(256) void bin_sorted_kernel(
    const int* __restrict__ idx, const float* __restrict__ vals,
    ull* __restrict__ packed, unsigned short* __restrict__ desc,
    int nnz, int nb)
{
    __shared__ int cnt[NB128_MAX];       // counters, then cursors
    __shared__ int off[NB128_MAX + 1];   // exclusive scan
    __shared__ int sm[256];

    int chunk = blockIdx.x;
    int base = chunk * CHUNK;
    int m = min(CHUNK, nnz - base);

    for (int i = threadIdx.x; i < nb; i += 256) cnt[i] = 0;
    __syncthreads();

    // load edges into registers, histogram superbuckets
    ull pv[EPT];
    int pb[EPT];
    #pragma unroll
    for (int j = 0; j < EPT; ++j) {
        int i = threadIdx.x + j * 256;
        pb[j] = -1;
        if (i < m) {
            int e = base + i;
            int r = idx[e];
            unsigned c = (unsigned)idx[nnz + e];
            unsigned vb = __float_as_uint(vals[e]);
            pv[j] = ((ull)vb << 32) | ((ull)c << SBSHIFT) | (unsigned)(r & 127);
            pb[j] = r >> SBSHIFT;
            atomicAdd(&cnt[pb[j]], 1);
        }
    }
    __syncthreads();

    // exclusive scan of cnt[0..nb) -> off[0..nb], 4 elems/thread (nb <= 1024)
    {
        int b4 = threadIdx.x * 4;
        int v0 = (b4 + 0 < nb) ? cnt[b4 + 0] : 0;
        int v1 = (b4 + 1 < nb) ? cnt[b4 + 1] : 0;
        int v2 = (b4 + 2 < nb) ? cnt[b4 + 2] : 0;
        int v3 = (b4 + 3 < nb) ? cnt[b4 + 3] : 0;
        int tot = v0 + v1 + v2 + v3;
        sm[threadIdx.x] = tot;
        __syncthreads();
        for (int o = 1; o < 256; o <<= 1) {
            int t = sm[threadIdx.x];
            int u = (threadIdx.x >= o) ? sm[threadIdx.x - o] : 0;
            __syncthreads();
            sm[threadIdx.x] = t + u;
            __syncthreads();
        }
        int ex = sm[threadIdx.x] - tot;
        if (b4 + 0 < nb) off[b4 + 0] = ex;
        if (b4 + 1 < nb) off[b4 + 1] = ex + v0;
        if (b4 + 2 < nb) off[b4 + 2] = ex + v0 + v1;
        if (b4 + 3 < nb) off[b4 + 3] = ex + v0 + v1 + v2;
        if (threadIdx.x == 0) off[nb] = m;
    }
    __syncthreads();

    // cursors
    for (int i = threadIdx.x; i < nb; i += 256) cnt[i] = off[i];
    __syncthreads();

    // scatter into the chunk's own contiguous window (full-line coverage)
    #pragma unroll
    for (int j = 0; j < EPT; ++j) {
        if (pb[j] >= 0) {
            int pos = atomicAdd(&cnt[pb[j]], 1);
            packed[(size_t)base + pos] = pv[j];
        }
    }

    // segment starts for this chunk (coalesced ushort writes)
    for (int i = threadIdx.x; i <= nb; i += 256)
        desc[(size_t)chunk * (nb + 1) + i] = (unsigned short)off[i];
}

// ---------- k2: segment-walk + filtered counting-sort + register accumulate ----------
__global__ __launch_bounds__(256) void spmm_seg_kernel(
    const unsigned short* __restrict__ desc,
    const ull* __restrict__ packed,
    const float* __restrict__ x, float* __restrict__ out,
    int N, int nb, int nchunk)
{
    __shared__ ull sp[MAXE];
    __shared__ int cnt[RPB];
    __shared__ int off[RPB];
    __shared__ int cur[RPB];
    __shared__ int segScan[NCH_MAX + 1];
    __shared__ unsigned short segStart[NCH_MAX];
    __shared__ int sm2[256];

    int wg = blockIdx.x;
    int j = wg >> 2;               // superbucket
    int mysub = wg & 3;            // 32-row slice
    int g = threadIdx.x >> 3;      // owned row-local index (32 groups)
    int q = threadIdx.x & 7;       // 4 columns each
    const float4* __restrict__ x4 = reinterpret_cast<const float4*>(x);

    // ---- Phase A: build segment table (2 chunk-slots per thread) ----
    {
        int t = threadIdx.x;
        int c0 = 2 * t, c1 = 2 * t + 1;
        int len0 = 0, len1 = 0;
        if (c0 < nchunk) {
            int a = desc[(size_t)c0 * (nb + 1) + j];
            int bnd = desc[(size_t)c0 * (nb + 1) + j + 1];
            segStart[c0] = (unsigned short)a;
            len0 = bnd - a;
        } else if (c0 < NCH_MAX) segStart[c0] = 0;
        if (c1 < nchunk) {
            int a = desc[(size_t)c1 * (nb + 1) + j];
            int bnd = desc[(size_t)c1 * (nb + 1) + j + 1];
            segStart[c1] = (unsigned short)a;
            len1 = bnd - a;
        } else if (c1 < NCH_MAX) segStart[c1] = 0;
        int tot = len0 + len1;
        sm2[t] = tot;
        __syncthreads();
        for (int o = 1; o < 256; o <<= 1) {
            int v = sm2[t];
            int u = (t >= o) ? sm2[t - o] : 0;
            __syncthreads();
            sm2[t] = v + u;
            __syncthreads();
        }
        int ex = sm2[t] - tot;
        segScan[c0] = ex;
        segScan[c1] = ex + len0;
        if (t == 255) segScan[NCH_MAX] = sm2[255];
        __syncthreads();
    }
    int total = segScan[NCH_MAX];

    float4 acc = make_float4(0.f, 0.f, 0.f, 0.f);

    // ---- Phase B: batched filter/sort/accumulate ----
    for (int bb = 0; bb < total; bb += MAXE) {
        int m = min(MAXE, total - bb);

        if (threadIdx.x < RPB) cnt[threadIdx.x] = 0;
        __syncthreads();

        ull pv[MAXE / 256];
        bool have[MAXE / 256];
        #pragma unroll
        for (int jj = 0; jj < MAXE / 256; ++jj) {
            int i = threadIdx.x + jj * 256;
            have[jj] = false;
            if (i < m) {
                int gi = bb + i;
                // binary search: max c in [0,511] with segScan[c] <= gi
                int c = 0;
                #pragma unroll
                for (int st = 256; st >= 1; st >>= 1) {
                    int nc2 = c + st;
                    if (nc2 <= NCH_MAX - 1 && segScan[nc2] <= gi) c = nc2;
                }
                ull p = packed[(size_t)c * CHUNK + (int)segStart[c] + (gi - segScan[c])];
                if ((int)((p >> BSHIFT) & 3) == mysub) {   // bits 5..6 of rloc7
                    pv[jj] = p;
                    have[jj] = true;
                    atomicAdd(&cnt[(int)(p & (RPB - 1))], 1);
                }
            }
        }
        __syncthreads();

        // exclusive scan of 32 counters (lanes 0..31 of wave 0)
        if (threadIdx.x < RPB) {
            int v = cnt[threadIdx.x];
            int sum = v;
            #pragma unroll
            for (int d2 = 1; d2 < RPB; d2 <<= 1) {
                int u = __shfl_up(sum, d2, 64);
                if ((int)threadIdx.x >= d2) sum += u;
            }
            off[threadIdx.x] = sum - v;
            cur[threadIdx.x] = sum - v;
        }
        __syncthreads();

        // scatter my kept edges into row-sorted order
        #pragma unroll
        for (int jj = 0; jj < MAXE / 256; ++jj) {
            if (have[jj]) {
                int rl = (int)(pv[jj] & (RPB - 1));
                int pos = atomicAdd(&cur[rl], 1);
                sp[pos] = pv[jj];
            }
        }
        __syncthreads();

        // group g accumulates its own row's segment — registers, no atomics
        int rs = off[g];
        int re = rs + cnt[g];
        int k = rs;
        for (; k + 3 < re; k += 4) {       // 4 gathers in flight
            ull p0 = sp[k], p1 = sp[k + 1], p2 = sp[k + 2], p3 = sp[k + 3];
            int c0 = (int)((p0 >> SBSHIFT) & 0x1ffff);
            int c1 = (int)((p1 >> SBSHIFT) & 0x1ffff);
            int c2 = (int)((p2 >> SBSHIFT) & 0x1ffff);
            int c3 = (int)((p3 >> SBSHIFT) & 0x1ffff);
            float v0 = __uint_as_float((unsigned)(p0 >> 32));
            float v1 = __uint_as_float((unsigned)(p1 >> 32));
            float v2 = __uint_as_float((unsigned)(p2 >> 32));
            float v3 = __uint_as_float((unsigned)(p3 >> 32));
            float4 a0 = x4[(size_t)c0 * (D / 4) + q];
            float4 a1 = x4[(size_t)c1 * (D / 4) + q];
            float4 a2 = x4[(size_t)c2 * (D / 4) + q];
            float4 a3 = x4[(size_t)c3 * (D / 4) + q];
            acc.x += v0 * a0.x; acc.y += v0 * a0.y; acc.z += v0 * a0.z; acc.w += v0 * a0.w;
            acc.x += v1 * a1.x; acc.y += v1 * a1.y; acc.z += v1 * a1.z; acc.w += v1 * a1.w;
            acc.x += v2 * a2.x; acc.y += v2 * a2.y; acc.z += v2 * a2.z; acc.w += v2 * a2.w;
            acc.x += v3 * a3.x; acc.y += v3 * a3.y; acc.z += v3 * a3.z; acc.w += v3 * a3.w;
        }
        for (; k < re; ++k) {
            ull p = sp[k];
            int c = (int)((p >> SBSHIFT) & 0x1ffff);
            float v = __uint_as_float((unsigned)(p >> 32));
            float4 a = x4[(size_t)c * (D / 4) + q];
            acc.x += v * a.x; acc.y += v * a.y; acc.z += v * a.z; acc.w += v * a.w;
        }
        __syncthreads();   // protect sp/cnt before next batch
    }

    int row = (j << SBSHIFT) + (mysub << BSHIFT) + g;
    if (row < N)
        reinterpret_cast<float4*>(out)[(size_t)row * (D / 4) + q] = acc;
}

// ---------- fallback: direct atomic scatter (round-1) ----------
__global__ __launch_bounds__(256) void spmm_scatter_kernel(
    const int* __restrict__ idx, const float* __restrict__ vals,
    const float* __restrict__ x, float* __restrict__ out, int nnz)
{
    int t = blockIdx.x * blockDim.x + threadIdx.x;
    int e = t >> 3;
    int q = t & 7;
    if (e >= nnz) return;
    int r = idx[e];
    int c = idx[nnz + e];
    float v = vals[e];
    const float4 xv = reinterpret_cast<const float4*>(x)[(size_t)c * (D / 4) + q];
    float* o = out + (size_t)r * D + q * 4;
    atomicAdd(o + 0, v * xv.x);
    atomicAdd(o + 1, v * xv.y);
    atomicAdd(o + 2, v * xv.z);
    atomicAdd(o + 3, v * xv.w);
}

static inline size_t align256(size_t v) { return (v + 255) & ~(size_t)255; }

extern "C" void kernel_launch(void* const* d_in, const int* in_sizes, int n_in,
                              void* d_out, int out_size, void* d_ws, size_t ws_size,
                              hipStream_t stream)
{
    const int* idx   = (const int*)d_in[0];
    const float* val = (const float*)d_in[1];
    const float* x   = (const float*)d_in[2];
    float* out       = (float*)d_out;

    const int nnz   = in_sizes[1];
    const int N     = out_size / D;
    const int nb128 = (N + 127) >> SBSHIFT;   // superbuckets
    const int nb32  = (N + 31) >> BSHIFT;     // spmm grid
    const int nchunk = (nnz + CHUNK - 1) / CHUNK;

    size_t off_packed = 0;
    size_t off_desc   = align256(off_packed + (size_t)nnz * 8);
    size_t ws_needed  = off_desc + (size_t)nchunk * (nb128 + 1) * 2;

    // col 17 bits; nb128 within scan width; nchunk within segment table
    if (ws_size < ws_needed || nb128 > NB128_MAX || nchunk > NCH_MAX || N > 131072) {
        hipMemsetAsync(d_out, 0, (size_t)out_size * sizeof(float), stream);
        const long long total = (long long)nnz * 8;
        spmm_scatter_kernel<<<(int)((total + 255) / 256), 256, 0, stream>>>(
            idx, val, x, out, nnz);
        return;
    }

    char* ws = (char*)d_ws;
    ull* packed = (ull*)(ws + off_packed);
    unsigned short* desc = (unsigned short*)(ws + off_desc);

    bin_sorted_kernel<<<nchunk, 256, 0, stream>>>(idx, val, packed, desc, nnz, nb128);
    spmm_seg_kernel<<<nb32, 256, 0, stream>>>(desc, packed, x, out, N, nb128, nchunk);
}

// Round 10
// 64.336 us; speedup vs baseline: 2.2394x; 1.1467x over previous
//
#include <hip/hip_runtime.h>

// out[N,32] = scatter_add over edges e: values[e] * x[cols[e], :] into row rows[e]
//
// Pipeline (superbucket = row >> 7, 128 rows, nb128 = ceil(N/128) = 782):
//   k1 bin_sorted : one WG per 4096-edge chunk. LDS counting sort by superbucket
//                   (counters+scan in LDS, edges in registers), then CONTIGUOUS
//                   write of the sorted chunk into packed[chunk*4096..] (write-amp
//                   1.0) + per-(chunk,bucket) ushort segment starts into desc.
//   k2 spmm_sb    : ONE 1024-thread block per superbucket (grid=782, 16 waves,
//                   2 blocks/CU = full occupancy). Streams the superbucket's
//                   edges exactly once via binary-search segment walk (no
//                   filtering, no redundancy), LDS counting-sorts each 2048-edge
//                   batch by the 7-bit row-local index, then each of 128 8-lane
//                   groups owns ONE row and accumulates in registers. No float
//                   atomics anywhere.
//
// indices: d_in[0] = int[2*NNZ], values: d_in[1] = float[NNZ], x: d_in[2] = float[N*32]

#define D 32
#define SBSHIFT 7
#define NB128_MAX 1024
#define CHUNK 4096              // edges per bin chunk (sorted unit)
#define EPT (CHUNK / 256)       // 16 edges per thread in bin
#define NCH_MAX 512             // max chunks (nnz <= 2.1M)
#define MAXB 2048               // sort-batch size in spmm (2 slots/thread)

typedef unsigned long long ull;

// ---------- k1: per-chunk counting sort by superbucket ----------
__global__ __launch_bounds__(256) void bin_sorted_kernel(
    const int* __restrict__ idx, const float* __restrict__ vals,
    ull* __restrict__ packed, unsigned short* __restrict__ desc,
    int nnz, int nb)
{
    __shared__ int cnt[NB128_MAX];       // counters, then cursors
    __shared__ int off[NB128_MAX + 1];   // exclusive scan
    __shared__ int sm[256];

    int chunk = blockIdx.x;
    int base = chunk * CHUNK;
    int m = min(CHUNK, nnz - base);

    for (int i = threadIdx.x; i < nb; i += 256) cnt[i] = 0;
    __syncthreads();

    // load edges into registers, histogram superbuckets
    ull pv[EPT];
    int pb[EPT];
    #pragma unroll
    for (int j = 0; j < EPT; ++j) {
        int i = threadIdx.x + j * 256;
        pb[j] = -1;
        if (i < m) {
            int e = base + i;
            int r = idx[e];
            unsigned c = (unsigned)idx[nnz + e];
            unsigned vb = __float_as_uint(vals[e]);
            pv[j] = ((ull)vb << 32) | ((ull)c << SBSHIFT) | (unsigned)(r & 127);
            pb[j] = r >> SBSHIFT;
            atomicAdd(&cnt[pb[j]], 1);
        }
    }
    __syncthreads();

    // exclusive scan of cnt[0..nb) -> off[0..nb], 4 elems/thread (nb <= 1024)
    {
        int b4 = threadIdx.x * 4;
        int v0 = (b4 + 0 < nb) ? cnt[b4 + 0] : 0;
        int v1 = (b4 + 1 < nb) ? cnt[b4 + 1] : 0;
        int v2 = (b4 + 2 < nb) ? cnt[b4 + 2] : 0;
        int v3 = (b4 + 3 < nb) ? cnt[b4 + 3] : 0;
        int tot = v0 + v1 + v2 + v3;
        sm[threadIdx.x] = tot;
        __syncthreads();
        for (int o = 1; o < 256; o <<= 1) {
            int t = sm[threadIdx.x];
            int u = (threadIdx.x >= o) ? sm[threadIdx.x - o] : 0;
            __syncthreads();
            sm[threadIdx.x] = t + u;
            __syncthreads();
        }
        int ex = sm[threadIdx.x] - tot;
        if (b4 + 0 < nb) off[b4 + 0] = ex;
        if (b4 + 1 < nb) off[b4 + 1] = ex + v0;
        if (b4 + 2 < nb) off[b4 + 2] = ex + v0 + v1;
        if (b4 + 3 < nb) off[b4 + 3] = ex + v0 + v1 + v2;
        if (threadIdx.x == 0) off[nb] = m;
    }
    __syncthreads();

    // cursors
    for (int i = threadIdx.x; i < nb; i += 256) cnt[i] = off[i];
    __syncthreads();

    // scatter into the chunk's own contiguous window (full-line coverage)
    #pragma unroll
    for (int j = 0; j < EPT; ++j) {
        if (pb[j] >= 0) {
            int pos = atomicAdd(&cnt[pb[j]], 1);
            packed[(size_t)base + pos] = pv[j];
        }
    }

    // segment starts for this chunk (coalesced ushort writes)
    for (int i = threadIdx.x; i <= nb; i += 256)
        desc[(size_t)chunk * (nb + 1) + i] = (unsigned short)off[i];
}

// ---------- k2: whole-superbucket counting-sort + register accumulate ----------
__global__ __launch_bounds__(1024, 8) void spmm_sb_kernel(
    const unsigned short* __restrict__ desc,
    const ull* __restrict__ packed,
    const float* __restrict__ x, float* __restrict__ out,
    int N, int nb, int nchunk)
{
    __shared__ ull sp[MAXB];
    __shared__ int cnt[128];
    __shared__ int off[128];
    __shared__ int cur[128];
    __shared__ int segScan[NCH_MAX + 1];
    __shared__ unsigned short segStart[NCH_MAX];
    __shared__ int sm2[NCH_MAX];

    int j = blockIdx.x;            // superbucket
    int t = threadIdx.x;
    int g = t >> 3;                // owned row-local index (128 groups)
    int q = t & 7;                 // 4 columns each
    const float4* __restrict__ x4 = reinterpret_cast<const float4*>(x);

    // ---- Phase A: segment table, 1 chunk-slot per thread ----
    int len = 0;
    if (t < nchunk) {
        int a  = desc[(size_t)t * (nb + 1) + j];
        int bd = desc[(size_t)t * (nb + 1) + j + 1];
        segStart[t] = (unsigned short)a;
        len = bd - a;
    } else if (t < NCH_MAX) {
        segStart[t] = 0;
    }
    if (t < NCH_MAX) sm2[t] = len;
    __syncthreads();
    for (int o = 1; o < NCH_MAX; o <<= 1) {
        int v = 0;
        if (t < NCH_MAX) { v = sm2[t]; if (t >= o) v += sm2[t - o]; }
        __syncthreads();
        if (t < NCH_MAX) sm2[t] = v;
        __syncthreads();
    }
    if (t < NCH_MAX) segScan[t] = sm2[t] - len;       // exclusive
    if (t == NCH_MAX - 1) segScan[NCH_MAX] = sm2[t];  // total
    __syncthreads();
    int total = segScan[NCH_MAX];

    float4 acc = make_float4(0.f, 0.f, 0.f, 0.f);

    // ---- Phase B: batched sort + accumulate (no filter — every edge is ours) ----
    for (int bb = 0; bb < total; bb += MAXB) {
        int m = min(MAXB, total - bb);

        if (t < 128) cnt[t] = 0;
        __syncthreads();

        ull pv[MAXB / 1024];
        bool have[MAXB / 1024];
        #pragma unroll
        for (int jj = 0; jj < MAXB / 1024; ++jj) {
            int i = t + jj * 1024;
            have[jj] = (i < m);
            if (have[jj]) {
                int gi = bb + i;
                // binary search: max c with segScan[c] <= gi
                int c = 0;
                #pragma unroll
                for (int st = NCH_MAX / 2; st >= 1; st >>= 1) {
                    int nc = c + st;
                    if (nc <= NCH_MAX - 1 && segScan[nc] <= gi) c = nc;
                }
                ull p = packed[(size_t)c * CHUNK + (int)segStart[c] + (gi - segScan[c])];
                pv[jj] = p;
                atomicAdd(&cnt[(int)(p & 127)], 1);
            }
        }
        __syncthreads();

        // exclusive scan of 128 counters (threads 0..127, Hillis-Steele in LDS)
        if (t < 128) sm2[t] = cnt[t];
        __syncthreads();
        for (int o = 1; o < 128; o <<= 1) {
            int v = 0;
            if (t < 128) { v = sm2[t]; if (t >= o) v += sm2[t - o]; }
            __syncthreads();
            if (t < 128) sm2[t] = v;
            __syncthreads();
        }
        if (t < 128) {
            int ex = sm2[t] - cnt[t];
            off[t] = ex;
            cur[t] = ex;
        }
        __syncthreads();

        // scatter into row-sorted order
        #pragma unroll
        for (int jj = 0; jj < MAXB / 1024; ++jj) {
            if (have[jj]) {
                int rl = (int)(pv[jj] & 127);
                int pos = atomicAdd(&cur[rl], 1);
                sp[pos] = pv[jj];
            }
        }
        __syncthreads();

        // group g accumulates its own row's segment — registers, no atomics
        int rs = off[g];
        int re = rs + cnt[g];
        int k = rs;
        for (; k + 3 < re; k += 4) {       // 4 gathers in flight
            ull p0 = sp[k], p1 = sp[k + 1], p2 = sp[k + 2], p3 = sp[k + 3];
            int c0 = (int)((p0 >> SBSHIFT) & 0x1ffff);
            int c1 = (int)((p1 >> SBSHIFT) & 0x1ffff);
            int c2 = (int)((p2 >> SBSHIFT) & 0x1ffff);
            int c3 = (int)((p3 >> SBSHIFT) & 0x1ffff);
            float v0 = __uint_as_float((unsigned)(p0 >> 32));
            float v1 = __uint_as_float((unsigned)(p1 >> 32));
            float v2 = __uint_as_float((unsigned)(p2 >> 32));
            float v3 = __uint_as_float((unsigned)(p3 >> 32));
            float4 a0 = x4[(size_t)c0 * (D / 4) + q];
            float4 a1 = x4[(size_t)c1 * (D / 4) + q];
            float4 a2 = x4[(size_t)c2 * (D / 4) + q];
            float4 a3 = x4[(size_t)c3 * (D / 4) + q];
            acc.x += v0 * a0.x; acc.y += v0 * a0.y; acc.z += v0 * a0.z; acc.w += v0 * a0.w;
            acc.x += v1 * a1.x; acc.y += v1 * a1.y; acc.z += v1 * a1.z; acc.w += v1 * a1.w;
            acc.x += v2 * a2.x; acc.y += v2 * a2.y; acc.z += v2 * a2.z; acc.w += v2 * a2.w;
            acc.x += v3 * a3.x; acc.y += v3 * a3.y; acc.z += v3 * a3.z; acc.w += v3 * a3.w;
        }
        for (; k < re; ++k) {
            ull p = sp[k];
            int c = (int)((p >> SBSHIFT) & 0x1ffff);
            float v = __uint_as_float((unsigned)(p >> 32));
            float4 a = x4[(size_t)c * (D / 4) + q];
            acc.x += v * a.x; acc.y += v * a.y; acc.z += v * a.z; acc.w += v * a.w;
        }
        __syncthreads();   // protect sp/cnt before next batch
    }

    int row = (j << SBSHIFT) + g;
    if (row < N)
        reinterpret_cast<float4*>(out)[(size_t)row * (D / 4) + q] = acc;
}

// ---------- fallback: direct atomic scatter (round-1) ----------
__global__ __launch_bounds__(256) void spmm_scatter_kernel(
    const int* __restrict__ idx, const float* __restrict__ vals,
    const float* __restrict__ x, float* __restrict__ out, int nnz)
{
    int t = blockIdx.x * blockDim.x + threadIdx.x;
    int e = t >> 3;
    int q = t & 7;
    if (e >= nnz) return;
    int r = idx[e];
    int c = idx[nnz + e];
    float v = vals[e];
    const float4 xv = reinterpret_cast<const float4*>(x)[(size_t)c * (D / 4) + q];
    float* o = out + (size_t)r * D + q * 4;
    atomicAdd(o + 0, v * xv.x);
    atomicAdd(o + 1, v * xv.y);
    atomicAdd(o + 2, v * xv.z);
    atomicAdd(o + 3, v * xv.w);
}

static inline size_t align256(size_t v) { return (v + 255) & ~(size_t)255; }

extern "C" void kernel_launch(void* const* d_in, const int* in_sizes, int n_in,
                              void* d_out, int out_size, void* d_ws, size_t ws_size,
                              hipStream_t stream)
{
    const int* idx   = (const int*)d_in[0];
    const float* val = (const float*)d_in[1];
    const float* x   = (const float*)d_in[2];
    float* out       = (float*)d_out;

    const int nnz   = in_sizes[1];
    const int N     = out_size / D;
    const int nb128 = (N + 127) >> SBSHIFT;   // superbuckets
    const int nchunk = (nnz + CHUNK - 1) / CHUNK;

    size_t off_packed = 0;
    size_t off_desc   = align256(off_packed + (size_t)nnz * 8);
    size_t ws_needed  = off_desc + (size_t)nchunk * (nb128 + 1) * 2;

    // col 17 bits; nb128 within scan width; nchunk within segment table
    if (ws_size < ws_needed || nb128 > NB128_MAX || nchunk > NCH_MAX || N > 131072) {
        hipMemsetAsync(d_out, 0, (size_t)out_size * sizeof(float), stream);
        const long long total = (long long)nnz * 8;
        spmm_scatter_kernel<<<(int)((total + 255) / 256), 256, 0, stream>>>(
            idx, val, x, out, nnz);
        return;
    }

    char* ws = (char*)d_ws;
    ull* packed = (ull*)(ws + off_packed);
    unsigned short* desc = (unsigned short*)(ws + off_desc);

    bin_sorted_kernel<<<nchunk, 256, 0, stream>>>(idx, val, packed, desc, nnz, nb128);
    spmm_sb_kernel<<<nb128, 1024, 0, stream>>>(desc, packed, x, out, N, nb128, nchunk);
}